// Round 11
// baseline (34.416 us; speedup 1.0000x reference)
//
#include <hip/hip_runtime.h>

#define C 32
#define H 192
#define W 192
#define HW (H*W)        // 36864
#define NPIX (HW*2)     // 73728
#define KK 7

// ---------------- K1 (exact R7): z[hw][o*2+n] = sum_c cw[o,c]*x[c][hw][n] ----------------
__global__ __launch_bounds__(256) void k1_mix(
    const float* __restrict__ x, const float* __restrict__ cw, float* __restrict__ z)
{
    __shared__ float wl[128];                    // wl[c*4+oo] = cw[ob+oo][c]
    const int b   = blockIdx.x;
    const int xcd = b & 7, idx = b >> 3;         // bijective (1152%8==0)
    const int hwblk = xcd * 18 + (idx >> 3);     // 0..143
    const int ob    = (idx & 7) * 4;             // o-pass of 4 channels
    const int tid   = threadIdx.x;

    if (tid < 128) wl[tid] = cw[(ob + (tid & 3)) * C + (tid >> 2)];
    __syncthreads();

    const int hw = hwblk * 256 + tid;
    const float2* x2 = reinterpret_cast<const float2*>(x);
    float2 xv[C];
#pragma unroll
    for (int c = 0; c < C; ++c) xv[c] = x2[(size_t)c * HW + hw];

    float acc[4][2];
#pragma unroll
    for (int oo = 0; oo < 4; ++oo) { acc[oo][0] = 0.f; acc[oo][1] = 0.f; }

#pragma unroll
    for (int c = 0; c < C; ++c) {
        const float4 wt = *reinterpret_cast<const float4*>(&wl[c * 4]);  // uniform broadcast
        acc[0][0] += wt.x * xv[c].x;  acc[0][1] += wt.x * xv[c].y;
        acc[1][0] += wt.y * xv[c].x;  acc[1][1] += wt.y * xv[c].y;
        acc[2][0] += wt.z * xv[c].x;  acc[2][1] += wt.z * xv[c].y;
        acc[3][0] += wt.w * xv[c].x;  acc[3][1] += wt.w * xv[c].y;
    }

    float* zp = z + (size_t)hw * 64 + ob * 2;    // 8 contiguous floats
    *reinterpret_cast<float4*>(zp)     = make_float4(acc[0][0], acc[0][1], acc[1][0], acc[1][1]);
    *reinterpret_cast<float4*>(zp + 4) = make_float4(acc[2][0], acc[2][1], acc[3][0], acc[3][1]);
}

// ---------------- K2 (exact R7): scalar weights, branchy edges ----------------
#define K2_BLOCKS 1152   // 192 rows x 6 wq
__global__ __launch_bounds__(256) void k2_conv(
    const float* __restrict__ z, const float* __restrict__ w1,
    const float* __restrict__ cb, float* __restrict__ out)
{
    __shared__ float tr[4][8 * 66];              // epilogue transpose only

    const int b  = blockIdx.x;
    const int l  = (b & 7) * (K2_BLOCKS / 8) + (b >> 3);  // XCD row bands (24 rows each)
    const int h  = l / 6;
    const int wq = l % 6;
    const int tid  = threadIdx.x;
    const int wv   = __builtin_amdgcn_readfirstlane(tid >> 6);  // uniform in SGPR
    const int lane = tid & 63;                   // o*2+n
    const int w0   = wq * 32 + wv * 8;

    float acc[8];
#pragma unroll
    for (int p = 0; p < 8; ++p) acc[p] = 0.f;

    const bool wedge = (w0 == 0) || (w0 == W - 8);   // scalar branch (w0 uniform)

#pragma unroll
    for (int i = 0; i < KK; ++i) {
        const int yy = h + i - 3;
        if (yy < 0 || yy >= H) continue;         // uniform per block

        float zw[14];
        if (!wedge) {
            const float* p = z + ((size_t)yy * W + (w0 - 3)) * 64 + lane;
#pragma unroll
            for (int k = 0; k < 14; ++k) zw[k] = p[k * 64];
        } else {
            const float* p = z + (size_t)yy * (W * 64) + lane;
#pragma unroll
            for (int k = 0; k < 14; ++k) {
                const int cc  = w0 - 3 + k;                    // uniform
                const int ccl = cc < 0 ? 0 : (cc > W - 1 ? W - 1 : cc);
                const float v = p[ccl * 64];
                zw[k] = (cc == ccl) ? v : 0.f;
            }
        }

        // weights: wave-uniform addresses -> scalar pipe
        const float* wp = w1 + (size_t)i * KK * HW + (size_t)h * W + w0;
#pragma unroll
        for (int j = 0; j < KK; ++j) {
#pragma unroll
            for (int px = 0; px < 8; ++px)
                acc[px] += wp[(size_t)j * HW + px] * zw[j + px];
        }
    }

    // epilogue: bias + per-wave LDS transpose -> 16B stores
    const float bias = cb[lane >> 1];
    float* trw = &tr[wv][0];
#pragma unroll
    for (int p = 0; p < 8; ++p) trw[p * 66 + lane] = acc[p] + bias;
    __syncthreads();

    const int o = lane >> 1, half = lane & 1;
    float v8[8];
#pragma unroll
    for (int m = 0; m < 8; ++m) {
        const int f = half * 8 + m;
        v8[m] = trw[(f >> 1) * 66 + o * 2 + (f & 1)];
    }
    float* obase = out + (size_t)o * NPIX + ((size_t)h * W + w0) * 2 + half * 8;
    *reinterpret_cast<float4*>(obase)     = make_float4(v8[0], v8[1], v8[2], v8[3]);
    *reinterpret_cast<float4*>(obase + 4) = make_float4(v8[4], v8[5], v8[6], v8[7]);
}

extern "C" void kernel_launch(void* const* d_in, const int* in_sizes, int n_in,
                              void* d_out, int out_size, void* d_ws, size_t ws_size,
                              hipStream_t stream) {
    const float* x  = (const float*)d_in[0];   // (C,H,W,2)
    const float* w1 = (const float*)d_in[1];   // (1,1,49,H,W)
    const float* cw = (const float*)d_in[2];   // (C_out, C_in)
    const float* cb = (const float*)d_in[3];   // (C,)
    float* z   = (float*)d_ws;                 // (HW, 64) transposed mix
    float* out = (float*)d_out;                // (C,H,W,2)

    hipLaunchKernelGGL(k1_mix, dim3(1152), dim3(256), 0, stream, x, cw, z);
    hipLaunchKernelGGL(k2_conv, dim3(K2_BLOCKS), dim3(256), 0, stream, z, w1, cb, out);
    // SPLIT-MEASUREMENT: second identical k2 launch (idempotent -> same output).
    // k2_time ~= (this round's dur_us) - 23.9 - launch_eps; k1 follows by subtraction.
    hipLaunchKernelGGL(k2_conv, dim3(K2_BLOCKS), dim3(256), 0, stream, z, w1, cb, out);
}

// Round 12
// 33.986 us; speedup vs baseline: 1.0126x; 1.0126x over previous
//
#include <hip/hip_runtime.h>

#define C 32
#define H 192
#define W 192
#define HW (H*W)        // 36864
#define NPIX (HW*2)     // 73728
#define KK 7
#define TH 3            // out rows per block
#define TW 16           // out cols per block
#define ZR (TH+6)       // 9  z-tile rows
#define ZC (TW+6)       // 22 z-tile cols
#define ZPX (ZR*ZC)     // 198 z pixels
#define ZSTR 68         // float stride per z pixel (16B aligned, spreads banks)
#define NBLK 768        // 64 h-tiles x 12 w-tiles; 768%8==0

__global__ __launch_bounds__(256) void fused(
    const float* __restrict__ x, const float* __restrict__ w1,
    const float* __restrict__ cw, const float* __restrict__ cb,
    float* __restrict__ out)
{
    __shared__ float zl[ZPX * ZSTR];             // 53.9 KB

    const int b   = blockIdx.x;
    const int l   = (b & 7) * (NBLK / 8) + (b >> 3);   // bijective XCD swizzle
    const int ht  = l / 12, wt = l % 12;
    const int h0  = ht * TH, w0 = wt * TW;
    const int tid = threadIdx.x;

    // ---------- phase 1: mix x -> z tile (thread = one z pixel, all 64 ch) ----------
    if (tid < ZPX) {
        const int r  = tid / ZC, cc = tid - r * ZC;
        const int y  = h0 - 3 + r;
        const int xc = w0 - 3 + cc;
        float acc[64];
#pragma unroll
        for (int e = 0; e < 64; ++e) acc[e] = 0.f;

        if ((unsigned)y < (unsigned)H && (unsigned)xc < (unsigned)W) {
            const float2* x2 = reinterpret_cast<const float2*>(x);
            const int pix = y * W + xc;
#pragma unroll
            for (int c0 = 0; c0 < C; c0 += 8) {
                float2 xv[8];
#pragma unroll
                for (int q = 0; q < 8; ++q) xv[q] = x2[(size_t)(c0 + q) * HW + pix];
#pragma unroll
                for (int o = 0; o < C; ++o) {
#pragma unroll
                    for (int q = 0; q < 8; ++q) {
                        const float wv_ = cw[o * C + c0 + q];   // uniform -> s_load (dwordx8 runs)
                        acc[2*o]   += wv_ * xv[q].x;
                        acc[2*o+1] += wv_ * xv[q].y;
                    }
                }
            }
        }
        float* zp = &zl[tid * ZSTR];
#pragma unroll
        for (int e = 0; e < 64; e += 4)
            *reinterpret_cast<float4*>(zp + e) = make_float4(acc[e], acc[e+1], acc[e+2], acc[e+3]);
    }
    __syncthreads();

    // ---------- phase 2: 7x7 per-pixel conv from z LDS (wave = 1 out row x 16 px, lane = ch) ----------
    const int wv   = __builtin_amdgcn_readfirstlane(tid >> 6);  // 0..3 (wave 3 idles here)
    const int lane = tid & 63;                   // ch = o*2+n
    float acc2[TW];
#pragma unroll
    for (int p = 0; p < TW; ++p) acc2[p] = 0.f;

    if (wv < TH) {
        const int hrow = h0 + wv;
#pragma unroll
        for (int i = 0; i < KK; ++i) {
            float zw[ZC];
#pragma unroll
            for (int k = 0; k < ZC; ++k)
                zw[k] = zl[((wv + i) * ZC + k) * ZSTR + lane];   // conflict-free b32

            const float* wp = w1 + (size_t)i * KK * HW + (size_t)hrow * W + w0;  // uniform -> s_load
#pragma unroll
            for (int j = 0; j < KK; ++j) {
#pragma unroll
                for (int p = 0; p < TW; ++p)
                    acc2[p] += wp[(size_t)j * HW + p] * zw[p + j];
            }
        }
    }
    __syncthreads();                             // all z reads done; overlay tr on zl

    // ---------- epilogue: per-wave transpose -> coalesced 16B stores ----------
    if (wv < TH) {
        const int hrow = h0 + wv;
        float* trw = &zl[wv * (TW * 66)];        // 16x66 floats per wave, inside zl
        const float bias = cb[lane >> 1];
#pragma unroll
        for (int p = 0; p < TW; ++p) trw[p * 66 + lane] = acc2[p] + bias;
        // same-wave LDS write->read: compiler inserts lgkmcnt wait; no barrier needed
        const int o = lane >> 1, half = lane & 1;
        float* obase = out + (size_t)o * NPIX + ((size_t)hrow * W + w0) * 2 + half * 16;
#pragma unroll
        for (int m = 0; m < 4; ++m) {
            float4 v;
            v.x = trw[(half * 8 + 2*m    ) * 66 + o * 2 + 0];
            v.y = trw[(half * 8 + 2*m    ) * 66 + o * 2 + 1];
            v.z = trw[(half * 8 + 2*m + 1) * 66 + o * 2 + 0];
            v.w = trw[(half * 8 + 2*m + 1) * 66 + o * 2 + 1];
            *reinterpret_cast<float4*>(obase + 4 * m) = v;
        }
    }
}

extern "C" void kernel_launch(void* const* d_in, const int* in_sizes, int n_in,
                              void* d_out, int out_size, void* d_ws, size_t ws_size,
                              hipStream_t stream) {
    const float* x  = (const float*)d_in[0];   // (C,H,W,2)
    const float* w1 = (const float*)d_in[1];   // (1,1,49,H,W)
    const float* cw = (const float*)d_in[2];   // (C_out, C_in)
    const float* cb = (const float*)d_in[3];   // (C,)
    float* out = (float*)d_out;                // (C,H,W,2)
    (void)d_ws; (void)ws_size;

    hipLaunchKernelGGL(fused, dim3(NBLK), dim3(256), 0, stream, x, w1, cw, cb, out);
}

// Round 13
// 24.827 us; speedup vs baseline: 1.3862x; 1.3689x over previous
//
#include <hip/hip_runtime.h>

#define C 32
#define H 192
#define W 192
#define HW (H*W)        // 36864
#define NPIX (HW*2)     // 73728
#define KK 7

// ---------------- K1 v2: single-pass-per-half channel mix ----------------
// thread = one pixel x 16 o-channels (both n) = 32 output floats = 128B contiguous store.
// 576 blocks x 128 thr; XCD n gets pixel band [n*4608, (n+1)*4608) for both halves
// (matches k2's h-band [24n, 24n+24)) -> z handoff is L2-local.
__global__ __launch_bounds__(128) void k1_mix(
    const float* __restrict__ x, const float* __restrict__ cw, float* __restrict__ z)
{
    const int b    = blockIdx.x;
    const int xcd  = b & 7, r = b >> 3;          // r in [0,72): 36 blocks half0, 36 half1
    const int half = (r >= 36);
    const int blk  = xcd * 36 + (half ? r - 36 : r);   // 0..287 within a half
    const int pix  = blk * 128 + threadIdx.x;    // 0..36863
    const int ob   = half * 16;                  // o channels [ob, ob+16)

    const float2* x2 = reinterpret_cast<const float2*>(x);

    float acc[16][2];
#pragma unroll
    for (int oo = 0; oo < 16; ++oo) { acc[oo][0] = 0.f; acc[oo][1] = 0.f; }

#pragma unroll
    for (int c0 = 0; c0 < C; c0 += 8) {
        float2 xv[8];
#pragma unroll
        for (int q = 0; q < 8; ++q) xv[q] = x2[(size_t)(c0 + q) * HW + pix];  // 512B/wave coalesced
#pragma unroll
        for (int oo = 0; oo < 16; ++oo) {
#pragma unroll
            for (int q = 0; q < 8; ++q) {
                const float wv_ = cw[(ob + oo) * C + c0 + q];   // block-uniform -> s_load
                acc[oo][0] += wv_ * xv[q].x;
                acc[oo][1] += wv_ * xv[q].y;
            }
        }
    }

    // 32 contiguous floats (one 128B line, single writer)
    float* zp = z + (size_t)pix * 64 + ob * 2;
#pragma unroll
    for (int e = 0; e < 16; e += 2)
        *reinterpret_cast<float4*>(zp + e * 2) =
            make_float4(acc[e][0], acc[e][1], acc[e+1][0], acc[e+1][1]);
}

// ---------------- K2 (byte-identical R7): scalar weights, branchy edges ----------------
#define K2_BLOCKS 1152   // 192 rows x 6 wq
__global__ __launch_bounds__(256) void k2_conv(
    const float* __restrict__ z, const float* __restrict__ w1,
    const float* __restrict__ cb, float* __restrict__ out)
{
    __shared__ float tr[4][8 * 66];              // epilogue transpose only

    const int b  = blockIdx.x;
    const int l  = (b & 7) * (K2_BLOCKS / 8) + (b >> 3);  // XCD row bands (24 rows each)
    const int h  = l / 6;
    const int wq = l % 6;
    const int tid  = threadIdx.x;
    const int wv   = __builtin_amdgcn_readfirstlane(tid >> 6);  // uniform in SGPR
    const int lane = tid & 63;                   // o*2+n
    const int w0   = wq * 32 + wv * 8;

    float acc[8];
#pragma unroll
    for (int p = 0; p < 8; ++p) acc[p] = 0.f;

    const bool wedge = (w0 == 0) || (w0 == W - 8);   // scalar branch (w0 uniform)

#pragma unroll
    for (int i = 0; i < KK; ++i) {
        const int yy = h + i - 3;
        if (yy < 0 || yy >= H) continue;         // uniform per block

        float zw[14];
        if (!wedge) {
            const float* p = z + ((size_t)yy * W + (w0 - 3)) * 64 + lane;
#pragma unroll
            for (int k = 0; k < 14; ++k) zw[k] = p[k * 64];
        } else {
            const float* p = z + (size_t)yy * (W * 64) + lane;
#pragma unroll
            for (int k = 0; k < 14; ++k) {
                const int cc  = w0 - 3 + k;                    // uniform
                const int ccl = cc < 0 ? 0 : (cc > W - 1 ? W - 1 : cc);
                const float v = p[ccl * 64];
                zw[k] = (cc == ccl) ? v : 0.f;
            }
        }

        // weights: wave-uniform addresses -> scalar pipe
        const float* wp = w1 + (size_t)i * KK * HW + (size_t)h * W + w0;
#pragma unroll
        for (int j = 0; j < KK; ++j) {
#pragma unroll
            for (int px = 0; px < 8; ++px)
                acc[px] += wp[(size_t)j * HW + px] * zw[j + px];
        }
    }

    // epilogue: bias + per-wave LDS transpose -> 16B stores
    const float bias = cb[lane >> 1];
    float* trw = &tr[wv][0];
#pragma unroll
    for (int p = 0; p < 8; ++p) trw[p * 66 + lane] = acc[p] + bias;
    __syncthreads();

    const int o = lane >> 1, half = lane & 1;
    float v8[8];
#pragma unroll
    for (int m = 0; m < 8; ++m) {
        const int f = half * 8 + m;
        v8[m] = trw[(f >> 1) * 66 + o * 2 + (f & 1)];
    }
    float* obase = out + (size_t)o * NPIX + ((size_t)h * W + w0) * 2 + half * 8;
    *reinterpret_cast<float4*>(obase)     = make_float4(v8[0], v8[1], v8[2], v8[3]);
    *reinterpret_cast<float4*>(obase + 4) = make_float4(v8[4], v8[5], v8[6], v8[7]);
}

extern "C" void kernel_launch(void* const* d_in, const int* in_sizes, int n_in,
                              void* d_out, int out_size, void* d_ws, size_t ws_size,
                              hipStream_t stream) {
    const float* x  = (const float*)d_in[0];   // (C,H,W,2)
    const float* w1 = (const float*)d_in[1];   // (1,1,49,H,W)
    const float* cw = (const float*)d_in[2];   // (C_out, C_in)
    const float* cb = (const float*)d_in[3];   // (C,)
    float* z   = (float*)d_ws;                 // (HW, 64) transposed mix
    float* out = (float*)d_out;                // (C,H,W,2)

    hipLaunchKernelGGL(k1_mix, dim3(576), dim3(128), 0, stream, x, cw, z);
    hipLaunchKernelGGL(k2_conv, dim3(K2_BLOCKS), dim3(256), 0, stream, z, w1, cb, out);
}